// Round 12
// baseline (191.980 us; speedup 1.0000x reference)
//
#include <hip/hip_runtime.h>

// GAT: B=256, N=64, K=12, D=128
// Algebra: wq_eff = Wq @ wa_q, wk_eff = Wk @ wa_k; V-projection commutes
// with the attention average: out = h_bar @ Wv + bv * (sum attn).
//
// R8 (resubmit x2; acquisition timeouts, never ran):
// wave-autonomous counted-vmcnt LDS pipeline (R7 post-mortem: its
// block-wide staging forced __syncthreads per tile = vmcnt(0) drain = still
// bursty; it never tested continuous issue). Here:
//  - each wave stages ITS OWN pair (6.6KB: 6x1KB neighbors + 512B node)
//    into its own 2 LDS slots -> zero cross-wave deps -> NO barrier in the
//    attention loop.
//  - schedule per pair: STAGE(p+1) -> s_waitcnt vmcnt(7) (stage(p) done,
//    stage(p+1) in flight; never drains to 0 in-loop, T4) -> ds_read_b128
//    x7 -> compute. Loads continuously outstanding.
//  - masks prefetched at prologue (4 vmem, counted in the first wait).
//  - LDS 62KB -> 2 blocks/CU -> 8 waves/CU; 2 waves/SIMD interleave the
//    serial shuffle chains.
// Decision rule: 25-38us => burstiness was the limiter, keep going;
// 55-62us => 6th structure at the same wall => ROOFLINE.

#define B_  256
#define N_  64
#define K_  12
#define D_  128
#define BN  (B_ * N_)          // 16384 (b,n) pairs
#define ROWS 16                // pairs per block; wave owns 4
#define HB_STRIDE 132          // 528B rows: 16B-aligned
#define SLOT_F 1664            // floats per slot: 12*128 + 128

// ws float layout: [0..127] wq_eff | [128..255] wk_eff | [256] cq | [257] ckb
// ---------------------------------------------------------------------------
__global__ void prep_kernel(const float* __restrict__ Wq, const float* __restrict__ bq,
                            const float* __restrict__ Wk, const float* __restrict__ bk,
                            const float* __restrict__ wa_q, const float* __restrict__ wa_k,
                            float* __restrict__ ws) {
    int g = blockIdx.x;
    int l = threadIdx.x;
    const float* row;
    const float* wa;
    float* outp;
    if (g < 128)      { row = Wq + g * D_;         wa = wa_q; outp = ws + g; }
    else if (g < 256) { row = Wk + (g - 128) * D_; wa = wa_k; outp = ws + 128 + (g - 128); }
    else if (g == 256){ row = bq;                  wa = wa_q; outp = ws + 256; }
    else              { row = bk;                  wa = wa_k; outp = ws + 257; }

    float2 r = ((const float2*)row)[l];
    float2 w = ((const float2*)wa)[l];
    float p = r.x * w.x + r.y * w.y;
    #pragma unroll
    for (int m = 1; m < 64; m <<= 1) p += __shfl_xor(p, m, 64);
    if (l == 0) *outp = p;
}

// direct HBM->LDS, 16B per lane
__device__ __forceinline__ void gll16(const float* g, float* l) {
    __builtin_amdgcn_global_load_lds(
        (const __attribute__((address_space(1))) unsigned int*)g,
        (__attribute__((address_space(3))) unsigned int*)l, 16, 0, 0);
}

// ---------------------------------------------------------------------------
// grid = BN/16 = 1024 blocks x 256 threads. Block owns 16 pairs; wave owns
// 4 (pairs wave*4+p). Lane l: half h=l>>5 covers neighbor slots {2i+h};
// li=l&31 owns features 4li..4li+3. 8-value reduce-scatter (3 stages +
// xor8 + xor16, all verified R4/R7) -> lane (l&7) holds one full dot.
__global__ void __launch_bounds__(256)
fused_kernel(const float* __restrict__ nodes, const float* __restrict__ neigh,
             const float* __restrict__ mask, const float* __restrict__ ba_p,
             const float* __restrict__ ws, const float* __restrict__ Wv,
             const float* __restrict__ bv, float* __restrict__ out) {
    __shared__ float slab[8][SLOT_F];       // 4 waves x 2 slots x 6656B = 53.2KB
    __shared__ float hb[ROWS * HB_STRIDE];  // 8.4KB pooled rows
    __shared__ float scL[ROWS];

    const int t    = threadIdx.x;
    const int wave = t >> 6;
    const int l    = t & 63;
    const int li   = l & 31;
    const int h    = l >> 5;
    const int j8   = l & 7;

    const float cq  = ws[256];
    const float ckb = ws[257];
    const float ba  = ba_p[0];
    const float cst = cq + ckb + ba;
    const float4 wqe4 = ((const float4*)ws)[li];          // wq_eff[4li..]
    const float4 wke4 = ((const float4*)(ws + 128))[li];  // wk_eff[4li..]

    const int base_pair = blockIdx.x * ROWS;
    const int idx0 = base_pair + wave * 4;                // wave's first pair

    // ---- prologue: 4 mask values (oldest vmem, retired by first wait) ----
    float mv0 = (j8 < 6) ? mask[(size_t)(idx0 + 0) * K_ + 2 * j8 + h] : 0.0f;
    float mv1 = (j8 < 6) ? mask[(size_t)(idx0 + 1) * K_ + 2 * j8 + h] : 0.0f;
    float mv2 = (j8 < 6) ? mask[(size_t)(idx0 + 2) * K_ + 2 * j8 + h] : 0.0f;
    float mv3 = (j8 < 6) ? mask[(size_t)(idx0 + 3) * K_ + 2 * j8 + h] : 0.0f;

    // ---- wave-local async stage of pair p into slot (p&1): 7 vmem instrs ----
    #define STAGE(p) do {                                                     \
        const int idx_ = idx0 + (p);                                          \
        float* sb_ = &slab[wave * 2 + ((p) & 1)][0];                          \
        const float* ns_ = neigh + (size_t)idx_ * (K_ * D_);                  \
        _Pragma("unroll")                                                     \
        for (int i_ = 0; i_ < 6; ++i_)                                        \
            gll16(ns_ + i_ * 256 + l * 4, sb_ + i_ * 256 + l * 4);            \
        if (l < 32)                                                           \
            gll16(nodes + (size_t)idx_ * D_ + l * 4, sb_ + 1536 + l * 4);     \
    } while (0)

    // ---- attention for pair p from its slot (math verified R4/R7) ----
    #define COMPUTE(p, MV) do {                                               \
        const float* sb_ = &slab[wave * 2 + ((p) & 1)][0];                    \
        const float4 nv_ = *(const float4*)(sb_ + 1536 + 4 * li);             \
        float4 x0_ = *(const float4*)(sb_ + (0 + h) * 128 + 4 * li);          \
        float4 x1_ = *(const float4*)(sb_ + (2 + h) * 128 + 4 * li);          \
        float4 x2_ = *(const float4*)(sb_ + (4 + h) * 128 + 4 * li);          \
        float4 x3_ = *(const float4*)(sb_ + (6 + h) * 128 + 4 * li);          \
        float4 x4_ = *(const float4*)(sb_ + (8 + h) * 128 + 4 * li);          \
        float4 x5_ = *(const float4*)(sb_ + (10 + h) * 128 + 4 * li);         \
        float v0 = x0_.x*wke4.x + x0_.y*wke4.y + x0_.z*wke4.z + x0_.w*wke4.w; \
        float v1 = x1_.x*wke4.x + x1_.y*wke4.y + x1_.z*wke4.z + x1_.w*wke4.w; \
        float v2 = x2_.x*wke4.x + x2_.y*wke4.y + x2_.z*wke4.z + x2_.w*wke4.w; \
        float v3 = x3_.x*wke4.x + x3_.y*wke4.y + x3_.z*wke4.z + x3_.w*wke4.w; \
        float v4 = x4_.x*wke4.x + x4_.y*wke4.y + x4_.z*wke4.z + x4_.w*wke4.w; \
        float v5 = x5_.x*wke4.x + x5_.y*wke4.y + x5_.z*wke4.z + x5_.w*wke4.w; \
        float v6 = nv_.x*wke4.x + nv_.y*wke4.y + nv_.z*wke4.z + nv_.w*wke4.w; \
        float v7 = nv_.x*wqe4.x + nv_.y*wqe4.y + nv_.z*wqe4.z + nv_.w*wqe4.w; \
        float A0, A1, A2, A3;                                                 \
        {                                                                     \
            const bool hi_ = (l & 1);                                         \
            float g0 = __shfl_xor(hi_ ? v0 : v1, 1, 64);                      \
            float g1 = __shfl_xor(hi_ ? v2 : v3, 1, 64);                      \
            float g2 = __shfl_xor(hi_ ? v4 : v5, 1, 64);                      \
            float g3 = __shfl_xor(hi_ ? v6 : v7, 1, 64);                      \
            A0 = (hi_ ? v1 : v0) + g0;                                        \
            A1 = (hi_ ? v3 : v2) + g1;                                        \
            A2 = (hi_ ? v5 : v4) + g2;                                        \
            A3 = (hi_ ? v7 : v6) + g3;                                        \
        }                                                                     \
        float B0, B1;                                                         \
        {                                                                     \
            const bool hi_ = (l & 2);                                         \
            float g0 = __shfl_xor(hi_ ? A0 : A1, 2, 64);                      \
            float g1 = __shfl_xor(hi_ ? A2 : A3, 2, 64);                      \
            B0 = (hi_ ? A1 : A0) + g0;                                        \
            B1 = (hi_ ? A3 : A2) + g1;                                        \
        }                                                                     \
        float c;                                                              \
        {                                                                     \
            const bool hi_ = (l & 4);                                         \
            float g = __shfl_xor(hi_ ? B0 : B1, 4, 64);                       \
            c = (hi_ ? B1 : B0) + g;                                          \
        }                                                                     \
        c += __shfl_xor(c, 8, 64);                                            \
        c += __shfl_xor(c, 16, 64);                                           \
        const float pq_  = __shfl(c, 7, 8);                                   \
        const float pkn_ = __shfl(c, 6, 8);                                   \
        const float base_ = pq_ + cst;                                        \
        float s0_ = base_ + pkn_;                                             \
        s0_ = (s0_ >= 0.0f) ? s0_ : 0.2f * s0_;                               \
        const float e0_ = __expf(s0_);                                        \
        float sj_ = base_ + c;                                                \
        sj_ = (sj_ >= 0.0f) ? sj_ : 0.2f * sj_;                               \
        const float ej_ = __expf(sj_) * (MV); /* MV=0 for j8>=6 */            \
        const float an_ = (h == 0) ? e0_ : 0.0f;                              \
        float ax = an_ * nv_.x, ay = an_ * nv_.y;                             \
        float az = an_ * nv_.z, aw = an_ * nv_.w;                             \
        float Se_ = 0.0f;                                                     \
        {                                                                     \
            float bi_;                                                        \
            bi_ = __shfl(ej_, 0, 8); Se_ += bi_;                              \
            ax += bi_*x0_.x; ay += bi_*x0_.y; az += bi_*x0_.z; aw += bi_*x0_.w; \
            bi_ = __shfl(ej_, 1, 8); Se_ += bi_;                              \
            ax += bi_*x1_.x; ay += bi_*x1_.y; az += bi_*x1_.z; aw += bi_*x1_.w; \
            bi_ = __shfl(ej_, 2, 8); Se_ += bi_;                              \
            ax += bi_*x2_.x; ay += bi_*x2_.y; az += bi_*x2_.z; aw += bi_*x2_.w; \
            bi_ = __shfl(ej_, 3, 8); Se_ += bi_;                              \
            ax += bi_*x3_.x; ay += bi_*x3_.y; az += bi_*x3_.z; aw += bi_*x3_.w; \
            bi_ = __shfl(ej_, 4, 8); Se_ += bi_;                              \
            ax += bi_*x4_.x; ay += bi_*x4_.y; az += bi_*x4_.z; aw += bi_*x4_.w; \
            bi_ = __shfl(ej_, 5, 8); Se_ += bi_;                              \
            ax += bi_*x5_.x; ay += bi_*x5_.y; az += bi_*x5_.z; aw += bi_*x5_.w; \
        }                                                                     \
        ax += __shfl_xor(ax, 32, 64);                                         \
        ay += __shfl_xor(ay, 32, 64);                                         \
        az += __shfl_xor(az, 32, 64);                                         \
        aw += __shfl_xor(aw, 32, 64);                                         \
        Se_ += __shfl_xor(Se_, 32, 64);                                       \
        const float S_   = e0_ + Se_;                                         \
        const float inv_ = 1.0f / (S_ + 1e-16f);                              \
        if (h == 0) {                                                         \
            const int lrow_ = wave * 4 + (p);                                 \
            float4 o_;                                                        \
            o_.x = ax * inv_;                                                 \
            o_.y = ay * inv_;                                                 \
            o_.z = az * inv_;                                                 \
            o_.w = aw * inv_;                                                 \
            *(float4*)(hb + lrow_ * HB_STRIDE + 4 * li) = o_;                 \
            if (li == 0) scL[lrow_] = S_ * inv_;                              \
        }                                                                     \
    } while (0)

    #define VWAIT(n) do {                                                     \
        asm volatile("s_waitcnt vmcnt(%0)" :: "i"(n) : "memory");             \
        __builtin_amdgcn_sched_barrier(0);                                    \
    } while (0)

    // ---- pipeline: never drain vmcnt to 0 inside the loop ----
    STAGE(0);                       // outstanding: masks(4) + s0(7)
    __builtin_amdgcn_sched_barrier(0);
    STAGE(1);                       // + s1(7) = 18
    VWAIT(7);                       // masks + s0 done; s1 in flight
    COMPUTE(0, mv0);
    __builtin_amdgcn_sched_barrier(0);
    STAGE(2);                       // s1(7) + s2(7) = 14  (slot0: reads of p0 retired)
    VWAIT(7);                       // s1 done; s2 in flight
    COMPUTE(1, mv1);
    __builtin_amdgcn_sched_barrier(0);
    STAGE(3);                       // s2(7) + s3(7) = 14
    VWAIT(7);                       // s2 done; s3 in flight
    COMPUTE(2, mv2);
    __builtin_amdgcn_sched_barrier(0);
    VWAIT(0);                       // tail: s3 done
    COMPUTE(3, mv3);
    #undef STAGE
    #undef COMPUTE
    #undef VWAIT
    __syncthreads();                // single block-wide sync before Phase B

    // ---- Phase B: out[16x128] = hb @ Wv + bv * scale ----
    // thread (rg=t>>5, cg=t&31) does rows {rg, rg+8}, cols 4cg..4cg+3.
    const int rg = t >> 5;
    const int cg = t & 31;
    const float4* wv4 = (const float4*)Wv;        // [k][32] of float4
    const float* hr0 = hb + rg * HB_STRIDE;
    const float* hr1 = hb + (rg + 8) * HB_STRIDE;

    float4 acc0 = make_float4(0.0f, 0.0f, 0.0f, 0.0f);
    float4 acc1 = make_float4(0.0f, 0.0f, 0.0f, 0.0f);
    #pragma unroll 8
    for (int kq = 0; kq < 32; ++kq) {
        const float4 a0 = *(const float4*)(hr0 + 4 * kq);
        const float4 a1 = *(const float4*)(hr1 + 4 * kq);
        #pragma unroll
        for (int e = 0; e < 4; ++e) {
            const float4 w = wv4[(4 * kq + e) * 32 + cg];
            const float f0 = (e == 0) ? a0.x : (e == 1) ? a0.y : (e == 2) ? a0.z : a0.w;
            const float f1 = (e == 0) ? a1.x : (e == 1) ? a1.y : (e == 2) ? a1.z : a1.w;
            acc0.x += f0 * w.x; acc0.y += f0 * w.y;
            acc0.z += f0 * w.z; acc0.w += f0 * w.w;
            acc1.x += f1 * w.x; acc1.y += f1 * w.y;
            acc1.z += f1 * w.z; acc1.w += f1 * w.w;
        }
    }

    const float4 bvv = ((const float4*)bv)[cg];
    {
        const float s = scL[rg];
        float4 o;
        o.x = acc0.x + bvv.x * s;
        o.y = acc0.y + bvv.y * s;
        o.z = acc0.z + bvv.z * s;
        o.w = acc0.w + bvv.w * s;
        *(float4*)(out + (size_t)(base_pair + rg) * D_ + cg * 4) = o;
    }
    {
        const float s = scL[rg + 8];
        float4 o;
        o.x = acc1.x + bvv.x * s;
        o.y = acc1.y + bvv.y * s;
        o.z = acc1.z + bvv.z * s;
        o.w = acc1.w + bvv.w * s;
        *(float4*)(out + (size_t)(base_pair + rg + 8) * D_ + cg * 4) = o;
    }
}

// ---------------------------------------------------------------------------
extern "C" void kernel_launch(void* const* d_in, const int* in_sizes, int n_in,
                              void* d_out, int out_size, void* d_ws, size_t ws_size,
                              hipStream_t stream) {
    const float* nodes = (const float*)d_in[0];
    const float* neigh = (const float*)d_in[1];
    const float* mask  = (const float*)d_in[2];
    const float* Wq    = (const float*)d_in[3];
    const float* bq    = (const float*)d_in[4];
    const float* Wk    = (const float*)d_in[5];
    const float* bk    = (const float*)d_in[6];
    const float* Wv    = (const float*)d_in[7];
    const float* bv    = (const float*)d_in[8];
    const float* wa_q  = (const float*)d_in[9];
    const float* wa_k  = (const float*)d_in[10];
    const float* ba    = (const float*)d_in[11];
    float* out = (float*)d_out;
    float* ws  = (float*)d_ws;

    prep_kernel<<<258, 64, 0, stream>>>(Wq, bq, Wk, bk, wa_q, wa_k, ws);
    fused_kernel<<<BN / ROWS, 256, 0, stream>>>(nodes, neigh, mask, ba, ws, Wv, bv, out);
}